// Round 1
// 484.535 us; speedup vs baseline: 1.0073x; 1.0073x over previous
//
#include <hip/hip_runtime.h>
#include <hip/hip_bf16.h>

#define N_TOKENS 65536
#define MAXF 512
#define OUTF 1024
#define NGROUP 4

typedef __attribute__((ext_vector_type(8))) short short8;   // 8 bf16 (4 VGPRs)
typedef __attribute__((ext_vector_type(4))) float floatx4;
typedef unsigned short ushort_t;
typedef unsigned int uint_t;

__device__ __forceinline__ uint_t f2bf(float f) {
    uint_t u = __float_as_uint(f);
    u += 0x7fffu + ((u >> 16) & 1u);   // RNE
    return u >> 16;
}

// ws layout (bytes):
//   bases:      0      (8 ints: group starts, bases[4]=65536)
//   blockHist:  4096   (256*4 ints)
//   blockStart: 8192   (256*4 ints)
//   lists:      16384  (65536 ints, compact group-sorted token ids)
//   xb:         1MiB   (K-PACKED bf16 rows: group g rows have stride K_g=64<<g)
//   wb:         1MiB+64MiB (K-PACKED bf16 weights, per-group starts wstart[])
#define OFF_BASES  0
#define OFF_BHIST  4096
#define OFF_BSTART 8192
#define OFF_LISTS  16384
#define OFF_XB     (1u<<20)
#define OFF_WB     ((1u<<20) + ((size_t)N_TOKENS*MAXF*2))
#define WS_FULL    (OFF_WB + (size_t)NGROUP*OUTF*MAXF*2)
#define WS_MIN     (OFF_LISTS + (size_t)N_TOKENS*4)

// packed weight starts (elems): 1024 * {0, 64, 192, 448}
__constant__ int c_wstart[4] = {0, 65536, 196608, 458752};

// ---------- phase 1: per-block histogram (no atomics) ----------
__global__ void hist_kernel(const int* __restrict__ sizes, int* __restrict__ blockHist) {
    __shared__ int h[4][NGROUP];
    int t = threadIdx.x, wave = t >> 6;
    int tok = blockIdx.x * 256 + t;
    int g = __ffs(sizes[tok]) - 7;     // 64->0,128->1,256->2,512->3
    #pragma unroll
    for (int gg = 0; gg < NGROUP; ++gg) {
        unsigned long long m = __ballot(g == gg);
        if ((t & 63) == 0) h[wave][gg] = __popcll(m);
    }
    __syncthreads();
    if (t < NGROUP)
        blockHist[blockIdx.x * NGROUP + t] = h[0][t] + h[1][t] + h[2][t] + h[3][t];
}

// ---------- phase 2: scan over 256 blocks x 4 groups (single block) ----------
__global__ void scan_kernel(const int* __restrict__ blockHist,
                            int* __restrict__ blockStart, int* __restrict__ bases) {
    __shared__ int4 sh[256];
    int t = threadIdx.x;
    int4 v = ((const int4*)blockHist)[t];
    sh[t] = v;
    __syncthreads();
    for (int d = 1; d < 256; d <<= 1) {
        int4 u = sh[t];
        int4 a = make_int4(0, 0, 0, 0);
        if (t >= d) a = sh[t - d];
        __syncthreads();
        u.x += a.x; u.y += a.y; u.z += a.z; u.w += a.w;
        sh[t] = u;
        __syncthreads();
    }
    int4 incl = sh[t];
    int4 tot = sh[255];
    int b0 = 0, b1 = tot.x, b2 = b1 + tot.y, b3 = b2 + tot.z, b4 = b3 + tot.w;
    blockStart[t * 4 + 0] = b0 + incl.x - v.x;
    blockStart[t * 4 + 1] = b1 + incl.y - v.y;
    blockStart[t * 4 + 2] = b2 + incl.z - v.z;
    blockStart[t * 4 + 3] = b3 + incl.w - v.w;
    if (t == 0) {
        bases[0] = b0; bases[1] = b1; bases[2] = b2; bases[3] = b3; bases[4] = b4;
    }
}

// ---------- phase 3: scatter token ids into compact lists (no atomics) ----------
__global__ void scatter_kernel(const int* __restrict__ sizes,
                               const int* __restrict__ blockStart,
                               int* __restrict__ lists) {
    __shared__ int wcnt[4][NGROUP];
    int t = threadIdx.x, wave = t >> 6, lane = t & 63;
    int tok = blockIdx.x * 256 + t;
    int g = __ffs(sizes[tok]) - 7;
    int pos = 0;
    #pragma unroll
    for (int gg = 0; gg < NGROUP; ++gg) {
        unsigned long long m = __ballot(g == gg);
        if (g == gg) pos = __popcll(m & ((1ull << lane) - 1ull));
        if (lane == 0) wcnt[wave][gg] = __popcll(m);
    }
    __syncthreads();
    int off = blockStart[blockIdx.x * 4 + g];
    for (int w = 0; w < wave; ++w) off += wcnt[w][g];
    lists[off + pos] = tok;
}

// ---------- convert+compact x -> bf16, K-PACKED rows, dense grid-stride ----------
// unit = 8 bf16 elems (32B fp32 read, 16B bf16 write); every lane fully busy.
__global__ void convx_kernel(const float* __restrict__ x, const int* __restrict__ bases,
                             const int* __restrict__ lists, ushort_t* __restrict__ xb) {
    int c0 = bases[1] - bases[0], c1 = bases[2] - bases[1],
        c2 = bases[3] - bases[2], c3 = bases[4] - bases[3];
    // units per group: c_g * K_g / 8
    int p1 = c0 << 3;
    int p2 = p1 + (c1 << 4);
    int p3 = p2 + (c2 << 5);
    int T  = p3 + (c3 << 6);
    // packed xb elem starts
    int xs1 = c0 << 6;
    int xs2 = xs1 + (c1 << 7);
    int xs3 = xs2 + (c2 << 8);
    int stride = gridDim.x * blockDim.x;
    for (int id = blockIdx.x * blockDim.x + threadIdx.x; id < T; id += stride) {
        int g, local, base, xs;
        if (id < p1)      { g = 0; local = id;      base = bases[0]; xs = 0;   }
        else if (id < p2) { g = 1; local = id - p1; base = bases[1]; xs = xs1; }
        else if (id < p3) { g = 2; local = id - p2; base = bases[2]; xs = xs2; }
        else              { g = 3; local = id - p3; base = bases[3]; xs = xs3; }
        int shift = 3 + g;                    // log2(units per row)
        int sl = local >> shift;              // slot within group
        int k  = (local - (sl << shift)) << 3;
        int tok = lists[base + sl];
        const floatx4* src = (const floatx4*)(x + (size_t)tok * MAXF + k);
        floatx4 a = src[0], b = src[1];
        short8 v;
        v[0] = (short)f2bf(a[0]); v[1] = (short)f2bf(a[1]);
        v[2] = (short)f2bf(a[2]); v[3] = (short)f2bf(a[3]);
        v[4] = (short)f2bf(b[0]); v[5] = (short)f2bf(b[1]);
        v[6] = (short)f2bf(b[2]); v[7] = (short)f2bf(b[3]);
        *(short8*)(xb + (size_t)xs + ((size_t)sl << (6 + g)) + k) = v;
    }
}

// ---------- convert weight -> bf16, K-PACKED ----------
// total units = 1024*(64+128+256+512)/8 = 122880 -> 480 blocks exact
__global__ void convw_kernel(const float* __restrict__ weight, ushort_t* __restrict__ wb) {
    int id = blockIdx.x * 256 + threadIdx.x;
    int g, local, ws;
    if (id < 8192)       { g = 0; local = id;         ws = 0;      }
    else if (id < 24576) { g = 1; local = id - 8192;  ws = 65536;  }
    else if (id < 57344) { g = 2; local = id - 24576; ws = 196608; }
    else                 { g = 3; local = id - 57344; ws = 458752; }
    int shift = 3 + g;
    int row = local >> shift;
    int k = (local - (row << shift)) << 3;
    const floatx4* src = (const floatx4*)(weight + (size_t)g * OUTF * MAXF + (size_t)row * MAXF + k);
    floatx4 a = src[0], b = src[1];
    short8 v;
    v[0] = (short)f2bf(a[0]); v[1] = (short)f2bf(a[1]);
    v[2] = (short)f2bf(a[2]); v[3] = (short)f2bf(a[3]);
    v[4] = (short)f2bf(b[0]); v[5] = (short)f2bf(b[1]);
    v[6] = (short)f2bf(b[2]); v[7] = (short)f2bf(b[3]);
    *(short8*)(wb + ws + ((size_t)row << (6 + g)) + k) = v;
}

#define GLOAD_LDS16(gptr, lptr)                                                \
    __builtin_amdgcn_global_load_lds(                                          \
        (const __attribute__((address_space(1))) uint_t*)(gptr),               \
        (__attribute__((address_space(3))) uint_t*)(lptr), 16, 0, 0)

// ---------- bf16 grouped GEMM: 256x256 tile, 8 waves, dbuf + prefetch ----------
// Flat 1-D grid over tiles; tile counts derived from bases in-kernel.
// Staged bytes = M*N*K*2*(2/256) — half of the 128x128 version.
__global__ __launch_bounds__(512, 1) void gemm_bf16_kernel(
    const ushort_t* __restrict__ xb, const ushort_t* __restrict__ wb,
    const float* __restrict__ bias, const int* __restrict__ bases,
    const int* __restrict__ lists, float* __restrict__ out) {

    const int c0 = bases[1] - bases[0], c1 = bases[2] - bases[1],
              c2 = bases[3] - bases[2], c3 = bases[4] - bases[3];
    // tiles per group: ceil(c/256) * 4 n-tiles
    const int t0 = ((c0 + 255) >> 8) << 2;
    const int t1 = ((c1 + 255) >> 8) << 2;
    const int t2 = ((c2 + 255) >> 8) << 2;
    const int t3 = ((c3 + 255) >> 8) << 2;
    // packed xb elem starts
    const int xs1 = c0 << 6;
    const int xs2 = xs1 + (c1 << 7);
    const int xs3 = xs2 + (c2 << 8);

    int id = blockIdx.x;
    int g, local, count, gbase, xs, wsb;
    if (id < t0)                { g = 0; local = id;                count = c0; gbase = bases[0]; xs = 0;   wsb = 0;      }
    else if (id < t0 + t1)      { g = 1; local = id - t0;           count = c1; gbase = bases[1]; xs = xs1; wsb = 65536;  }
    else if (id < t0 + t1 + t2) { g = 2; local = id - t0 - t1;      count = c2; gbase = bases[2]; xs = xs2; wsb = 196608; }
    else if (id < t0 + t1 + t2 + t3)
                                { g = 3; local = id - t0 - t1 - t2; count = c3; gbase = bases[3]; xs = xs3; wsb = 458752; }
    else return;

    const int mt = local >> 2, nt = local & 3;
    const int m_base = mt << 8;
    const int n_base = nt << 8;
    const int K_log = 6 + g;
    const int nsteps = 1 << (g + 1);           // K/32
    const int rows = min(256, count - m_base);

    // 2 x (As 16KB + Bs 16KB) = 64 KB exactly (static LDS limit)
    __shared__ ushort_t As[2][256 * 32];
    __shared__ ushort_t Bs[2][256 * 32];

    const int t = threadIdx.x;
    const int wave = t >> 6, lane = t & 63;
    const int wm = wave >> 2, wn = wave & 3;   // 2 x 4 wave grid
    const int quad = lane >> 4, l16 = lane & 15;
    const int rsub = lane >> 2;                // row within 16-row staging chunk
    const int kq   = (lane & 3) * 8;           // bf16 elem offset (16B chunk)

    // staging source pointers (K-invariant; add k0 each step)
    const ushort_t* aptr[2];
    const ushort_t* bptr[2];
    #pragma unroll
    for (int j = 0; j < 2; ++j) {
        int br = wave * 32 + j * 16;
        int ar = min(m_base + br + rsub, count - 1);
        aptr[j] = xb + (size_t)xs + ((size_t)ar << K_log) + kq;
        int nr = n_base + br + rsub;
        bptr[j] = wb + (size_t)wsb + ((size_t)nr << K_log) + kq;
    }

    floatx4 acc[8][4];
    #pragma unroll
    for (int i = 0; i < 8; ++i)
        #pragma unroll
        for (int j = 0; j < 4; ++j) acc[i][j] = (floatx4)(0.0f);

    // prologue stage into buf 0
    #pragma unroll
    for (int j = 0; j < 2; ++j) {
        int br = wave * 32 + j * 16;
        GLOAD_LDS16(aptr[j], &As[0][br * 32]);
        GLOAD_LDS16(bptr[j], &Bs[0][br * 32]);
    }
    __syncthreads();   // drains vmcnt before barrier

    int buf = 0;
    for (int s = 0; s < nsteps; ++s) {
        if (s + 1 < nsteps) {
            int k0 = (s + 1) << 5;
            #pragma unroll
            for (int j = 0; j < 2; ++j) {
                int br = wave * 32 + j * 16;
                GLOAD_LDS16(aptr[j] + k0, &As[buf ^ 1][br * 32]);
                GLOAD_LDS16(bptr[j] + k0, &Bs[buf ^ 1][br * 32]);
            }
        }
        short8 af[8], bf[4];
        #pragma unroll
        for (int mi = 0; mi < 8; ++mi)
            af[mi] = *(const short8*)&As[buf][(wm * 128 + mi * 16 + l16) * 32 + quad * 8];
        #pragma unroll
        for (int ni = 0; ni < 4; ++ni)
            bf[ni] = *(const short8*)&Bs[buf][(wn * 64 + ni * 16 + l16) * 32 + quad * 8];
        #pragma unroll
        for (int mi = 0; mi < 8; ++mi)
            #pragma unroll
            for (int ni = 0; ni < 4; ++ni)
                acc[mi][ni] = __builtin_amdgcn_mfma_f32_16x16x32_bf16(
                    af[mi], bf[ni], acc[mi][ni], 0, 0, 0);
        __syncthreads();   // one drain+barrier per K-step (prefetch in flight above)
        buf ^= 1;
    }

    // epilogue: token ids read directly (L2-hot, wave-broadcast per row)
    #pragma unroll
    for (int ni = 0; ni < 4; ++ni) {
        int col = n_base + wn * 64 + ni * 16 + l16;
        float bv = bias[g * OUTF + col];
        #pragma unroll
        for (int mi = 0; mi < 8; ++mi) {
            int mloc = wm * 128 + mi * 16 + quad * 4;
            #pragma unroll
            for (int r = 0; r < 4; ++r) {
                int m = mloc + r;
                if (m < rows) {
                    int tok = lists[gbase + m_base + m];
                    out[(size_t)tok * OUTF + col] = acc[mi][ni][r] + bv;
                }
            }
        }
    }
}

// ---------- fallback: fp32 gather GEMM (round-1 style, flat lists) ----------
__global__ __launch_bounds__(256) void gemm_fp32_kernel(
    const float* __restrict__ x, const float* __restrict__ weight,
    const float* __restrict__ bias, const int* __restrict__ bases,
    const int* __restrict__ lists, float* __restrict__ out) {

    const int g = blockIdx.z;
    const int gbase = bases[g];
    const int count = bases[g + 1] - gbase;
    const int m_base = blockIdx.y * 128;
    if (m_base >= count) return;
    const int n_base = blockIdx.x * 128;
    const int K = 64 << g;
    const int rows = min(128, count - m_base);

    __shared__ ushort_t As[128][40];
    __shared__ ushort_t Bs[128][40];
    __shared__ int idxs[128];

    const int t = threadIdx.x;
    if (t < 128) idxs[t] = (t < rows) ? lists[gbase + m_base + t] : lists[gbase + m_base];
    __syncthreads();

    const int wave = t >> 6, lane = t & 63;
    const int wm = wave >> 1, wn = wave & 1;
    const int quad = lane >> 4, l16 = lane & 15;

    floatx4 acc[4][4];
    #pragma unroll
    for (int i = 0; i < 4; ++i)
        #pragma unroll
        for (int j = 0; j < 4; ++j) acc[i][j] = (floatx4)(0.0f);

    const float* wg = weight + (size_t)g * OUTF * MAXF;

    for (int k0 = 0; k0 < K; k0 += 32) {
        #pragma unroll
        for (int rep = 0; rep < 4; ++rep) {
            int id = t + rep * 256;
            int row = id >> 3;
            int kqq = id & 7;
            floatx4 av = *(const floatx4*)(x + (size_t)idxs[row] * MAXF + k0 + kqq * 4);
            unsigned long long pa = (unsigned long long)f2bf(av[0]) |
                ((unsigned long long)f2bf(av[1]) << 16) |
                ((unsigned long long)f2bf(av[2]) << 32) |
                ((unsigned long long)f2bf(av[3]) << 48);
            *(unsigned long long*)&As[row][kqq * 4] = pa;
            floatx4 bvv = *(const floatx4*)(wg + (size_t)(n_base + row) * MAXF + k0 + kqq * 4);
            unsigned long long pb = (unsigned long long)f2bf(bvv[0]) |
                ((unsigned long long)f2bf(bvv[1]) << 16) |
                ((unsigned long long)f2bf(bvv[2]) << 32) |
                ((unsigned long long)f2bf(bvv[3]) << 48);
            *(unsigned long long*)&Bs[row][kqq * 4] = pb;
        }
        __syncthreads();

        short8 af[4], bf[4];
        #pragma unroll
        for (int mi = 0; mi < 4; ++mi)
            af[mi] = *(const short8*)&As[wm * 64 + mi * 16 + l16][quad * 8];
        #pragma unroll
        for (int ni = 0; ni < 4; ++ni)
            bf[ni] = *(const short8*)&Bs[wn * 64 + ni * 16 + l16][quad * 8];
        #pragma unroll
        for (int mi = 0; mi < 4; ++mi)
            #pragma unroll
            for (int ni = 0; ni < 4; ++ni)
                acc[mi][ni] = __builtin_amdgcn_mfma_f32_16x16x32_bf16(
                    af[mi], bf[ni], acc[mi][ni], 0, 0, 0);
        __syncthreads();
    }

    #pragma unroll
    for (int ni = 0; ni < 4; ++ni) {
        int col = n_base + wn * 64 + ni * 16 + l16;
        float bv = bias[g * OUTF + col];
        #pragma unroll
        for (int mi = 0; mi < 4; ++mi) {
            int mloc = wm * 64 + mi * 16 + quad * 4;
            #pragma unroll
            for (int r = 0; r < 4; ++r) {
                int m = mloc + r;
                if (m < rows)
                    out[(size_t)idxs[m] * OUTF + col] = acc[mi][ni][r] + bv;
            }
        }
    }
}

extern "C" void kernel_launch(void* const* d_in, const int* in_sizes, int n_in,
                              void* d_out, int out_size, void* d_ws, size_t ws_size,
                              hipStream_t stream) {
    const float* x      = (const float*)d_in[0];
    const int*   sizes  = (const int*)d_in[1];
    const float* weight = (const float*)d_in[2];
    const float* bias   = (const float*)d_in[3];
    float* out = (float*)d_out;

    char* ws = (char*)d_ws;
    int* bases      = (int*)(ws + OFF_BASES);
    int* blockHist  = (int*)(ws + OFF_BHIST);
    int* blockStart = (int*)(ws + OFF_BSTART);
    int* lists      = (int*)(ws + OFF_LISTS);
    ushort_t* xb    = (ushort_t*)(ws + OFF_XB);
    ushort_t* wb    = (ushort_t*)(ws + OFF_WB);

    hist_kernel<<<N_TOKENS / 256, 256, 0, stream>>>(sizes, blockHist);
    scan_kernel<<<1, 256, 0, stream>>>(blockHist, blockStart, bases);
    scatter_kernel<<<N_TOKENS / 256, 256, 0, stream>>>(sizes, blockStart, lists);

    if (ws_size >= WS_FULL) {
        convw_kernel<<<480, 256, 0, stream>>>(weight, wb);
        convx_kernel<<<2048, 256, 0, stream>>>(x, bases, lists, xb);
        // flat tile grid upper bound: 4 * (ceil(65536/256) + 3) = 1036
        gemm_bf16_kernel<<<1036, 512, 0, stream>>>(xb, wb, bias, bases, lists, out);
    } else {
        dim3 grid(OUTF / 128, N_TOKENS / 128, NGROUP);
        gemm_fp32_kernel<<<grid, 256, 0, stream>>>(x, weight, bias, bases, lists, out);
    }
}

// Round 2
// 475.729 us; speedup vs baseline: 1.0260x; 1.0185x over previous
//
#include <hip/hip_runtime.h>
#include <hip/hip_bf16.h>

#define N_TOKENS 65536
#define MAXF 512
#define OUTF 1024
#define NGROUP 4

typedef __attribute__((ext_vector_type(8))) short short8;   // 8 bf16 (4 VGPRs)
typedef __attribute__((ext_vector_type(4))) float floatx4;
typedef unsigned short ushort_t;
typedef unsigned int uint_t;

__device__ __forceinline__ uint_t f2bf(float f) {
    uint_t u = __float_as_uint(f);
    u += 0x7fffu + ((u >> 16) & 1u);   // RNE
    return u >> 16;
}

// ws layout (bytes):
//   cnt:    0       (4 ints: per-group counts, atomic; zeroed via hipMemsetAsync)
//   lists:  16384   (4 * 65536 ints: per-group token id arrays, group g at g*65536)
//   xb:     2MiB    (K-PACKED bf16 rows, group-prefix packed)
//   wb:     2MiB+64MiB (K-PACKED bf16 weights, per-group starts {0,64,192,448}*1024)
#define OFF_CNT    0
#define OFF_LISTS  16384
#define OFF_XB     (2u<<20)
#define OFF_WB     ((2u<<20) + ((size_t)N_TOKENS*MAXF*2))
#define WS_FULL    (OFF_WB + (size_t)NGROUP*OUTF*MAXF*2)
#define WS_MIN     (OFF_LISTS + (size_t)NGROUP*N_TOKENS*4)

// ---------- fused hist+scan+scatter: per-group dense lists via atomics ----------
__global__ void prep_kernel(const int* __restrict__ sizes, int* __restrict__ cnt,
                            int* __restrict__ lists) {
    __shared__ int wcnt[4][NGROUP];
    __shared__ int gbase[NGROUP];
    int t = threadIdx.x, wave = t >> 6, lane = t & 63;
    int tok = blockIdx.x * 256 + t;
    int g = __ffs(sizes[tok]) - 7;     // 64->0,128->1,256->2,512->3
    int pos = 0;
    #pragma unroll
    for (int gg = 0; gg < NGROUP; ++gg) {
        unsigned long long m = __ballot(g == gg);
        if (g == gg) pos = __popcll(m & ((1ull << lane) - 1ull));
        if (lane == 0) wcnt[wave][gg] = __popcll(m);
    }
    __syncthreads();
    if (t < NGROUP) {
        int tot = wcnt[0][t] + wcnt[1][t] + wcnt[2][t] + wcnt[3][t];
        gbase[t] = atomicAdd(&cnt[t], tot);   // device-scope, disjoint ranges
    }
    __syncthreads();
    int off = gbase[g];
    for (int w = 0; w < wave; ++w) off += wcnt[w][g];
    lists[(g << 16) + off + pos] = tok;
}

// ---------- fused conversion: weights (ids < 122880) then x, K-PACKED ----------
__global__ void conv_kernel(const float* __restrict__ x, const float* __restrict__ weight,
                            const int* __restrict__ cnt, const int* __restrict__ lists,
                            ushort_t* __restrict__ xb, ushort_t* __restrict__ wb) {
    int c0 = cnt[0], c1 = cnt[1], c2 = cnt[2], c3 = cnt[3];
    int p1 = c0 << 3;
    int p2 = p1 + (c1 << 4);
    int p3 = p2 + (c2 << 5);
    int xT = p3 + (c3 << 6);
    int T = 122880 + xT;
    int xs1 = c0 << 6;
    int xs2 = xs1 + (c1 << 7);
    int xs3 = xs2 + (c2 << 8);
    int stride = gridDim.x * blockDim.x;
    for (int id = blockIdx.x * blockDim.x + threadIdx.x; id < T; id += stride) {
        const floatx4* src;
        ushort_t* dst;
        if (id < 122880) {
            int g, local, wsb;
            if (id < 8192)       { g = 0; local = id;         wsb = 0;      }
            else if (id < 24576) { g = 1; local = id - 8192;  wsb = 65536;  }
            else if (id < 57344) { g = 2; local = id - 24576; wsb = 196608; }
            else                 { g = 3; local = id - 57344; wsb = 458752; }
            int shift = 3 + g;
            int row = local >> shift;
            int k = (local - (row << shift)) << 3;
            src = (const floatx4*)(weight + (size_t)g * OUTF * MAXF + (size_t)row * MAXF + k);
            dst = wb + wsb + ((size_t)row << (6 + g)) + k;
        } else {
            int xid = id - 122880;
            int g, local, xs;
            if (xid < p1)      { g = 0; local = xid;      xs = 0;   }
            else if (xid < p2) { g = 1; local = xid - p1; xs = xs1; }
            else if (xid < p3) { g = 2; local = xid - p2; xs = xs2; }
            else               { g = 3; local = xid - p3; xs = xs3; }
            int shift = 3 + g;
            int sl = local >> shift;
            int k = (local - (sl << shift)) << 3;
            int tok = lists[(g << 16) + sl];
            src = (const floatx4*)(x + (size_t)tok * MAXF + k);
            dst = xb + (size_t)xs + ((size_t)sl << (6 + g)) + k;
        }
        floatx4 a = src[0], b = src[1];
        short8 v;
        v[0] = (short)f2bf(a[0]); v[1] = (short)f2bf(a[1]);
        v[2] = (short)f2bf(a[2]); v[3] = (short)f2bf(a[3]);
        v[4] = (short)f2bf(b[0]); v[5] = (short)f2bf(b[1]);
        v[6] = (short)f2bf(b[2]); v[7] = (short)f2bf(b[3]);
        *(short8*)dst = v;
    }
}

#define GLOAD_LDS16(gptr, lptr)                                                \
    __builtin_amdgcn_global_load_lds(                                          \
        (const __attribute__((address_space(1))) uint_t*)(gptr),               \
        (__attribute__((address_space(3))) uint_t*)(lptr), 16, 0, 0)

// ---------- bf16 grouped GEMM: 256x256 tile, 3-buffer depth-2 counted-vmcnt ----
// LDS (dynamic 99328 B): 3 x {As 16K | Bs 16K} + oidx 1K.
// XOR swizzle (16B granule): physical q = logical q ^ ((row>>1)&3), applied on
// BOTH the global_load_lds source offset and the fragment-read address (rule #21).
__global__ __launch_bounds__(512, 1) void gemm_bf16_kernel(
    const ushort_t* __restrict__ xb, const ushort_t* __restrict__ wb,
    const float* __restrict__ bias, const int* __restrict__ cnt,
    const int* __restrict__ lists, float* __restrict__ out) {

    extern __shared__ char sh[];

    const int c0 = cnt[0], c1 = cnt[1], c2 = cnt[2], c3 = cnt[3];
    const int t0 = ((c0 + 255) >> 8) << 2;
    const int t1 = ((c1 + 255) >> 8) << 2;
    const int t2 = ((c2 + 255) >> 8) << 2;
    const int t3 = ((c3 + 255) >> 8) << 2;
    const int xs1 = c0 << 6;
    const int xs2 = xs1 + (c1 << 7);
    const int xs3 = xs2 + (c2 << 8);

    int id = blockIdx.x;
    int g, local, count, xs, wsb;
    if (id < t0)                { g = 0; local = id;                count = c0; xs = 0;   wsb = 0;      }
    else if (id < t0 + t1)      { g = 1; local = id - t0;           count = c1; xs = xs1; wsb = 65536;  }
    else if (id < t0 + t1 + t2) { g = 2; local = id - t0 - t1;      count = c2; xs = xs2; wsb = 196608; }
    else if (id < t0 + t1 + t2 + t3)
                                { g = 3; local = id - t0 - t1 - t2; count = c3; xs = xs3; wsb = 458752; }
    else return;

    const int mt = local >> 2, nt = local & 3;
    const int m_base = mt << 8;
    const int n_base = nt << 8;
    const int K_log = 6 + g;
    const int nsteps = 1 << (g + 1);           // K/32 (>= 2)
    const int rows = min(256, count - m_base);

    const int t = threadIdx.x;
    const int wave = t >> 6, lane = t & 63;
    const int wm = wave >> 2, wn = wave & 3;   // 2 x 4 wave grid
    const int quad = lane >> 4, l16 = lane & 15;
    const int rsub = lane >> 2;                            // row in 16-row chunk
    const int kq = (((lane & 3) ^ ((lane >> 3) & 3)) << 3); // swizzled src granule
    const int rp = (l16 >> 1) & 3;                          // read-side swizzle term

    int* oidx = (int*)(sh + 98304);

    // epilogue token ids -> LDS (issued FIRST so it's the oldest vmem op)
    if (t < 256) {
        int m = m_base + t;
        oidx[t] = (m < count) ? lists[(g << 16) + m] : 0;
    }

    // staging source pointers (K-invariant; add k0 each step)
    const ushort_t* aptr[2];
    const ushort_t* bptr[2];
    #pragma unroll
    for (int j = 0; j < 2; ++j) {
        int br = wave * 32 + j * 16;
        int ar = min(m_base + br + rsub, count - 1);
        aptr[j] = xb + (size_t)xs + ((size_t)ar << K_log) + kq;
        bptr[j] = wb + (size_t)wsb + ((size_t)(n_base + br + rsub) << K_log) + kq;
    }

    floatx4 acc[8][4];
    #pragma unroll
    for (int i = 0; i < 8; ++i)
        #pragma unroll
        for (int j = 0; j < 4; ++j) acc[i][j] = (floatx4)(0.0f);

    // prologue: stage steps 0 and 1 (depth-2)
    #pragma unroll
    for (int j = 0; j < 2; ++j) {
        int br = wave * 32 + j * 16;
        GLOAD_LDS16(aptr[j], sh + br * 64);
        GLOAD_LDS16(bptr[j], sh + 16384 + br * 64);
    }
    if (nsteps > 1) {
        #pragma unroll
        for (int j = 0; j < 2; ++j) {
            int br = wave * 32 + j * 16;
            GLOAD_LDS16(aptr[j] + 32, sh + 32768 + br * 64);
            GLOAD_LDS16(bptr[j] + 32, sh + 32768 + 16384 + br * 64);
        }
    }

    int buf = 0;
    for (int s = 0; s < nsteps; ++s) {
        // counted wait: oldest 4 staging loads (this step's buffer) must be done;
        // next buffer's 4 may stay in flight. lgkmcnt(0) closes the WAR window
        // (all our ds_reads/ds_writes complete before we pass the barrier).
        if (s + 1 < nsteps)
            asm volatile("s_waitcnt vmcnt(4) lgkmcnt(0)" ::: "memory");
        else
            asm volatile("s_waitcnt vmcnt(0) lgkmcnt(0)" ::: "memory");
        __builtin_amdgcn_s_barrier();
        asm volatile("" ::: "memory");

        const ushort_t* Ab = (const ushort_t*)(sh + buf * 32768);
        const ushort_t* Bb = (const ushort_t*)(sh + buf * 32768 + 16384);
        short8 af[8], bfr[4];
        #pragma unroll
        for (int mi = 0; mi < 8; ++mi)
            af[mi] = *(const short8*)&Ab[(wm * 128 + mi * 16 + l16) * 32 + ((quad ^ rp) << 3)];
        #pragma unroll
        for (int ni = 0; ni < 4; ++ni)
            bfr[ni] = *(const short8*)&Bb[(wn * 64 + ni * 16 + l16) * 32 + ((quad ^ rp) << 3)];

        #pragma unroll
        for (int mi = 0; mi < 8; ++mi)
            #pragma unroll
            for (int ni = 0; ni < 4; ++ni)
                acc[mi][ni] = __builtin_amdgcn_mfma_f32_16x16x32_bf16(
                    af[mi], bfr[ni], acc[mi][ni], 0, 0, 0);

        // stage step s+2 into buffer (buf+2)%3 (read last at iter s-1; all waves
        // are past the iter-s barrier, so that read is fully retired)
        if (s + 2 < nsteps) {
            int k0 = (s + 2) << 5;
            int bn = buf + 2; if (bn >= 3) bn -= 3;
            char* dstA = sh + bn * 32768;
            #pragma unroll
            for (int j = 0; j < 2; ++j) {
                int br = wave * 32 + j * 16;
                GLOAD_LDS16(aptr[j] + k0, dstA + br * 64);
                GLOAD_LDS16(bptr[j] + k0, dstA + 16384 + br * 64);
            }
        }
        buf = (buf == 2) ? 0 : buf + 1;
    }

    // epilogue: bias + scatter to out rows (oidx from LDS; 64B aligned segments)
    #pragma unroll
    for (int ni = 0; ni < 4; ++ni) {
        int col = n_base + wn * 64 + ni * 16 + l16;
        float bv = bias[g * OUTF + col];
        #pragma unroll
        for (int mi = 0; mi < 8; ++mi) {
            int mloc = wm * 128 + mi * 16 + quad * 4;
            #pragma unroll
            for (int r = 0; r < 4; ++r) {
                int m = mloc + r;
                if (m < rows)
                    out[(size_t)oidx[m] * OUTF + col] = acc[mi][ni][r] + bv;
            }
        }
    }
}

// ---------- fallback: fp32 gather GEMM (per-group lists) ----------
__global__ __launch_bounds__(256) void gemm_fp32_kernel(
    const float* __restrict__ x, const float* __restrict__ weight,
    const float* __restrict__ bias, const int* __restrict__ cnt,
    const int* __restrict__ lists, float* __restrict__ out) {

    const int g = blockIdx.z;
    const int count = cnt[g];
    const int m_base = blockIdx.y * 128;
    if (m_base >= count) return;
    const int n_base = blockIdx.x * 128;
    const int K = 64 << g;
    const int rows = min(128, count - m_base);

    __shared__ ushort_t As[128][40];
    __shared__ ushort_t Bs[128][40];
    __shared__ int idxs[128];

    const int t = threadIdx.x;
    if (t < 128) idxs[t] = (t < rows) ? lists[(g << 16) + m_base + t]
                                      : lists[(g << 16) + m_base];
    __syncthreads();

    const int wave = t >> 6, lane = t & 63;
    const int wm = wave >> 1, wn = wave & 1;
    const int quad = lane >> 4, l16 = lane & 15;

    floatx4 acc[4][4];
    #pragma unroll
    for (int i = 0; i < 4; ++i)
        #pragma unroll
        for (int j = 0; j < 4; ++j) acc[i][j] = (floatx4)(0.0f);

    const float* wg = weight + (size_t)g * OUTF * MAXF;

    for (int k0 = 0; k0 < K; k0 += 32) {
        #pragma unroll
        for (int rep = 0; rep < 4; ++rep) {
            int id = t + rep * 256;
            int row = id >> 3;
            int kqq = id & 7;
            floatx4 av = *(const floatx4*)(x + (size_t)idxs[row] * MAXF + k0 + kqq * 4);
            unsigned long long pa = (unsigned long long)f2bf(av[0]) |
                ((unsigned long long)f2bf(av[1]) << 16) |
                ((unsigned long long)f2bf(av[2]) << 32) |
                ((unsigned long long)f2bf(av[3]) << 48);
            *(unsigned long long*)&As[row][kqq * 4] = pa;
            floatx4 bvv = *(const floatx4*)(wg + (size_t)(n_base + row) * MAXF + k0 + kqq * 4);
            unsigned long long pb = (unsigned long long)f2bf(bvv[0]) |
                ((unsigned long long)f2bf(bvv[1]) << 16) |
                ((unsigned long long)f2bf(bvv[2]) << 32) |
                ((unsigned long long)f2bf(bvv[3]) << 48);
            *(unsigned long long*)&Bs[row][kqq * 4] = pb;
        }
        __syncthreads();

        short8 af[4], bfr[4];
        #pragma unroll
        for (int mi = 0; mi < 4; ++mi)
            af[mi] = *(const short8*)&As[wm * 64 + mi * 16 + l16][quad * 8];
        #pragma unroll
        for (int ni = 0; ni < 4; ++ni)
            bfr[ni] = *(const short8*)&Bs[wn * 64 + ni * 16 + l16][quad * 8];
        #pragma unroll
        for (int mi = 0; mi < 4; ++mi)
            #pragma unroll
            for (int ni = 0; ni < 4; ++ni)
                acc[mi][ni] = __builtin_amdgcn_mfma_f32_16x16x32_bf16(
                    af[mi], bfr[ni], acc[mi][ni], 0, 0, 0);
        __syncthreads();
    }

    #pragma unroll
    for (int ni = 0; ni < 4; ++ni) {
        int col = n_base + wn * 64 + ni * 16 + l16;
        float bv = bias[g * OUTF + col];
        #pragma unroll
        for (int mi = 0; mi < 4; ++mi) {
            int mloc = wm * 64 + mi * 16 + quad * 4;
            #pragma unroll
            for (int r = 0; r < 4; ++r) {
                int m = mloc + r;
                if (m < rows)
                    out[(size_t)idxs[m] * OUTF + col] = acc[mi][ni][r] + bv;
            }
        }
    }
}

extern "C" void kernel_launch(void* const* d_in, const int* in_sizes, int n_in,
                              void* d_out, int out_size, void* d_ws, size_t ws_size,
                              hipStream_t stream) {
    const float* x      = (const float*)d_in[0];
    const int*   sizes  = (const int*)d_in[1];
    const float* weight = (const float*)d_in[2];
    const float* bias   = (const float*)d_in[3];
    float* out = (float*)d_out;

    char* ws = (char*)d_ws;
    int* cnt   = (int*)(ws + OFF_CNT);
    int* lists = (int*)(ws + OFF_LISTS);
    ushort_t* xb = (ushort_t*)(ws + OFF_XB);
    ushort_t* wb = (ushort_t*)(ws + OFF_WB);

    hipMemsetAsync(ws + OFF_CNT, 0, NGROUP * sizeof(int), stream);
    prep_kernel<<<N_TOKENS / 256, 256, 0, stream>>>(sizes, cnt, lists);

    if (ws_size >= WS_FULL) {
        static int attr_done = 0;
        if (!attr_done) {
            hipFuncSetAttribute((const void*)gemm_bf16_kernel,
                                hipFuncAttributeMaxDynamicSharedMemorySize, 99328);
            attr_done = 1;
        }
        conv_kernel<<<2048, 256, 0, stream>>>(x, weight, cnt, lists, xb, wb);
        // flat tile grid upper bound: 4 * (ceil(65536/256) + 3) = 1036
        gemm_bf16_kernel<<<1036, 512, 99328, stream>>>(xb, wb, bias, cnt, lists, out);
    } else {
        dim3 grid(OUTF / 128, N_TOKENS / 128, NGROUP);
        gemm_fp32_kernel<<<grid, 256, 0, stream>>>(x, weight, bias, cnt, lists, out);
    }
}